// Round 1
// baseline (505.385 us; speedup 1.0000x reference)
//
#include <hip/hip_runtime.h>
#include <hip/hip_bf16.h>
#include <stdint.h>

// ---------------------------------------------------------------------------
// MHA forward, B=2 S=2048 E=1024 H=16 D=64, fp32 in/out, bf16 MFMA internally.
// Pipeline: cvt(f32->bf16) -> pack mask bits -> QKV proj GEMM (z=3) ->
//           flash attention (swapped QK^T, online softmax fp32) -> out proj.
// ---------------------------------------------------------------------------

typedef __bf16 bf16x8 __attribute__((ext_vector_type(8)));
typedef __bf16 bf16x4 __attribute__((ext_vector_type(4)));
typedef float  f32x4  __attribute__((ext_vector_type(4)));
typedef unsigned int u32x4 __attribute__((ext_vector_type(4)));

#define MFMA16(a, b, c) __builtin_amdgcn_mfma_f32_16x16x32_bf16((a), (b), (c), 0, 0, 0)

static constexpr int kB = 2, kS = 2048, kE = 1024, kH = 16, kD = 64;
static constexpr int kM = kB * kS;          // 4096 rows
static constexpr int kMaskWordsPerRow = kS / 64;  // 32

// ---- async global->LDS (16B per lane, wave-uniform LDS base) --------------
__device__ __forceinline__ void gload_lds16(const void* g, void* l) {
  __builtin_amdgcn_global_load_lds(
      (const __attribute__((address_space(1))) unsigned int*)g,
      (__attribute__((address_space(3))) unsigned int*)l, 16, 0, 0);
}

__device__ __forceinline__ unsigned pack_bf16x2(float a, float b) {
  unsigned short lo = __builtin_bit_cast(unsigned short, (__bf16)a);
  unsigned short hi = __builtin_bit_cast(unsigned short, (__bf16)b);
  return (unsigned)lo | ((unsigned)hi << 16);
}

// ---------------------------------------------------------------------------
// Kernel 1: f32 -> bf16 conversion for q,k,v,Wq,Wk,Wv,Wo (segment = blockIdx.y)
// ---------------------------------------------------------------------------
__global__ __launch_bounds__(256) void cvt_kernel(
    const float* __restrict__ q, const float* __restrict__ k, const float* __restrict__ v,
    const float* __restrict__ wq, const float* __restrict__ wk,
    const float* __restrict__ wv, const float* __restrict__ wo,
    __bf16* __restrict__ qb, __bf16* __restrict__ kb, __bf16* __restrict__ vb,
    __bf16* __restrict__ wqb, __bf16* __restrict__ wkb,
    __bf16* __restrict__ wvb, __bf16* __restrict__ wob) {
  const int z = blockIdx.y;
  const float* src; __bf16* dst; int n;
  switch (z) {
    case 0: src = q;  dst = qb;  n = kM * kE; break;
    case 1: src = k;  dst = kb;  n = kM * kE; break;
    case 2: src = v;  dst = vb;  n = kM * kE; break;
    case 3: src = wq; dst = wqb; n = kE * kE; break;
    case 4: src = wk; dst = wkb; n = kE * kE; break;
    case 5: src = wv; dst = wvb; n = kE * kE; break;
    default: src = wo; dst = wob; n = kE * kE; break;
  }
  const int n4 = n >> 2;
  const int stride = gridDim.x * blockDim.x;
  for (int i = blockIdx.x * blockDim.x + threadIdx.x; i < n4; i += stride) {
    float4 f = ((const float4*)src)[i];
    bf16x4 o = {(__bf16)f.x, (__bf16)f.y, (__bf16)f.z, (__bf16)f.w};
    ((bf16x4*)dst)[i] = o;
  }
}

// ---------------------------------------------------------------------------
// Kernel 2: mask int32 [B,S,S] -> u64 bitmask [B,S,S/64] via wave ballot
// ---------------------------------------------------------------------------
__global__ __launch_bounds__(256) void pack_mask_kernel(
    const int* __restrict__ mask, unsigned long long* __restrict__ mw) {
  const int lane = threadIdx.x & 63;
  const int wid = (blockIdx.x * blockDim.x + threadIdx.x) >> 6;
  const int nwaves = (gridDim.x * blockDim.x) >> 6;
  const int nwords = kB * kS * kMaskWordsPerRow;  // 131072
  for (int w = wid; w < nwords; w += nwaves) {
    int v = mask[(size_t)w * 64 + lane];
    unsigned long long bits = __ballot(v != 0);
    if (lane == 0) mw[w] = bits;
  }
}

// ---------------------------------------------------------------------------
// Kernel 3/5: C = A[4096,1024] @ W^T[1024,1024] + bias   (NT, bf16 MFMA)
// 128x128 tile, BK=32, 4 waves (2x2), global_load_lds staging.
// mode 0: -> Qh [B,H,S,D] bf16, scaled by 1/8      (A=A0,W=W0,bias=b0)
// mode 1: -> Kh [B,H,S,D] bf16                     (A=A1,...)
// mode 2: -> Vt [B,H,D,S] bf16                     (A=A2,...)
// mode 3: -> OF f32 [4096,1024]                    (A=A0,...)
// ---------------------------------------------------------------------------
__global__ __launch_bounds__(256) void gemm_bt(
    const __bf16* __restrict__ A0, const __bf16* __restrict__ A1, const __bf16* __restrict__ A2,
    const __bf16* __restrict__ W0, const __bf16* __restrict__ W1, const __bf16* __restrict__ W2,
    const float* __restrict__ b0, const float* __restrict__ b1, const float* __restrict__ b2,
    __bf16* __restrict__ O0, __bf16* __restrict__ O1, __bf16* __restrict__ O2,
    float* __restrict__ OF, int mode_base) {
  const int z = blockIdx.z;
  const int mode = mode_base + z;
  const __bf16* A = (z == 0) ? A0 : (z == 1) ? A1 : A2;
  const __bf16* W = (z == 0) ? W0 : (z == 1) ? W1 : W2;
  const float* bias = (z == 0) ? b0 : (z == 1) ? b1 : b2;
  __bf16* OutB = (z == 0) ? O0 : (z == 1) ? O1 : O2;
  const float scale = (mode == 0) ? 0.125f : 1.0f;

  const int n0 = blockIdx.x * 128;
  const int m0 = blockIdx.y * 128;
  const int tid = threadIdx.x;
  const int wave = tid >> 6, lane = tid & 63;
  const int g = lane >> 4, qi = lane & 15;
  const int wm = wave >> 1, wn = wave & 1;

  __shared__ __align__(16) __bf16 As[128 * 32];
  __shared__ __align__(16) __bf16 Bs[128 * 32];

  f32x4 acc[4][4];
#pragma unroll
  for (int i = 0; i < 4; ++i)
#pragma unroll
    for (int j = 0; j < 4; ++j) acc[i][j] = (f32x4){0.f, 0.f, 0.f, 0.f};

  for (int k0 = 0; k0 < kE; k0 += 32) {
    // stage A and B tiles: 512 chunks of 16B each, 2 per thread per tile
#pragma unroll
    for (int j = 0; j < 2; ++j) {
      const int c = j * 256 + tid;           // chunk id (lane-contiguous)
      const int r = c >> 2, sl = c & 3;      // row, 16B slot within 64B row
      const int ldsbase = (j * 256 + wave * 64) * 8;  // elements
      gload_lds16(&A[(size_t)(m0 + r) * kE + k0 + sl * 8], &As[ldsbase]);
      gload_lds16(&W[(size_t)(n0 + r) * kE + k0 + sl * 8], &Bs[ldsbase]);
    }
    __syncthreads();

    bf16x8 af[4], bf[4];
#pragma unroll
    for (int mi = 0; mi < 4; ++mi)
      af[mi] = *(const bf16x8*)&As[(wm * 64 + mi * 16 + qi) * 32 + g * 8];
#pragma unroll
    for (int nj = 0; nj < 4; ++nj)
      bf[nj] = *(const bf16x8*)&Bs[(wn * 64 + nj * 16 + qi) * 32 + g * 8];
#pragma unroll
    for (int mi = 0; mi < 4; ++mi)
#pragma unroll
      for (int nj = 0; nj < 4; ++nj)
        acc[mi][nj] = MFMA16(af[mi], bf[nj], acc[mi][nj]);
    __syncthreads();
  }

  // epilogue
#pragma unroll
  for (int nj = 0; nj < 4; ++nj) {
    const int ncol = n0 + wn * 64 + nj * 16 + qi;
    const float bn = bias[ncol];
    const int hh = ncol >> 6, dd = ncol & 63;
#pragma unroll
    for (int mi = 0; mi < 4; ++mi) {
#pragma unroll
      for (int r = 0; r < 4; ++r) {
        const int mrow = m0 + wm * 64 + mi * 16 + g * 4 + r;
        const float vv = (acc[mi][nj][r] + bn) * scale;
        if (mode <= 1) {
          const int bb = mrow >> 11, ss = mrow & 2047;
          OutB[((((size_t)bb * kH + hh) * kS + ss) << 6) + dd] = (__bf16)vv;
        } else if (mode == 2) {
          const int bb = mrow >> 11, ss = mrow & 2047;
          OutB[((((size_t)bb * kH + hh) * kD + dd) << 11) + ss] = (__bf16)vv;
        } else {
          OF[(size_t)mrow * kE + ncol] = vv;
        }
      }
    }
  }
}

// ---------------------------------------------------------------------------
// Kernel 4: flash attention. 4 waves/block, each wave owns 16 q-rows.
// Swapped QK^T: st = mfma(K, Q) -> st[kv][q], q = lane&15 (lane-uniform state).
// K/Vt fragments read directly from global (L2-resident, 512KB per head).
// ---------------------------------------------------------------------------
__global__ __launch_bounds__(256) void attn_kernel(
    const __bf16* __restrict__ Qh, const __bf16* __restrict__ Kh,
    const __bf16* __restrict__ Vt, const unsigned long long* __restrict__ mw,
    __bf16* __restrict__ Ob) {
  const int wave = threadIdx.x >> 6, lane = threadIdx.x & 63;
  const int g = lane >> 4, qi = lane & 15;
  const int bh = blockIdx.y, b = bh >> 4, h = bh & 15;
  const int q = blockIdx.x * 64 + wave * 16 + qi;

  const __bf16* Qp = Qh + (size_t)bh * kS * kD;
  const __bf16* Kp = Kh + (size_t)bh * kS * kD;
  const __bf16* Vp = Vt + (size_t)bh * kD * kS;
  const unsigned long long* mrow = mw + (size_t)(b * kS + q) * kMaskWordsPerRow;

  // Q fragments (B-operand), loaded once; 1/8 scale pre-folded into Qh.
  bf16x8 qf0 = *(const bf16x8*)&Qp[(size_t)q * kD + g * 8];
  bf16x8 qf1 = *(const bf16x8*)&Qp[(size_t)q * kD + 32 + g * 8];

  f32x4 acc[4];  // out^T: rows d = f*16+g*4+r, col q
#pragma unroll
  for (int f = 0; f < 4; ++f) acc[f] = (f32x4){0.f, 0.f, 0.f, 0.f};
  float mrun = -3.0e38f, den = 0.f;

  for (int kv0 = 0; kv0 < kS; kv0 += 64) {
    // --- QK^T (swapped): st[f] covers kv rows f*16..f*16+15, col = q ---
    float s[16];
#pragma unroll
    for (int f = 0; f < 4; ++f) {
      const __bf16* kr = &Kp[(size_t)(kv0 + f * 16 + qi) * kD];
      bf16x8 ka = *(const bf16x8*)&kr[g * 8];
      bf16x8 kb2 = *(const bf16x8*)&kr[32 + g * 8];
      f32x4 st = (f32x4){0.f, 0.f, 0.f, 0.f};
      st = MFMA16(ka, qf0, st);
      st = MFMA16(kb2, qf1, st);
      const unsigned long long w = mrow[kv0 >> 6];
#pragma unroll
      for (int r = 0; r < 4; ++r) {
        float v = st[r];
        s[f * 4 + r] = ((w >> (f * 16 + g * 4 + r)) & 1ull) ? v : -1.0e9f;
      }
    }
    // --- online softmax (per q-column; reduce across the 4 lane-groups) ---
    float tm = s[0];
#pragma unroll
    for (int i = 1; i < 16; ++i) tm = fmaxf(tm, s[i]);
    tm = fmaxf(tm, __shfl_xor(tm, 16));
    tm = fmaxf(tm, __shfl_xor(tm, 32));
    const float mn = fmaxf(mrun, tm);
    const float alpha = __expf(mrun - mn);
    float tsum = 0.f;
#pragma unroll
    for (int i = 0; i < 16; ++i) {
      s[i] = __expf(s[i] - mn);
      tsum += s[i];
    }
    tsum += __shfl_xor(tsum, 16);
    tsum += __shfl_xor(tsum, 32);
    den = den * alpha + tsum;
    mrun = mn;
#pragma unroll
    for (int f = 0; f < 4; ++f) acc[f] *= alpha;

    // --- P (st-layout) -> bf16 PV b-fragments via cross-lane shuffle ---
    unsigned pk[4][2];
#pragma unroll
    for (int f = 0; f < 4; ++f) {
      pk[f][0] = pack_bf16x2(s[f * 4 + 0], s[f * 4 + 1]);
      pk[f][1] = pack_bf16x2(s[f * 4 + 2], s[f * 4 + 3]);
    }
#pragma unroll
    for (int c = 0; c < 2; ++c) {
      unsigned bw[4];
#pragma unroll
      for (int t = 0; t < 4; ++t) {
        const int src = qi + 16 * ((t >> 1) + 2 * (g & 1));
        const int vA = __shfl((int)pk[2 * c + 0][t & 1], src);
        const int vB = __shfl((int)pk[2 * c + 1][t & 1], src);
        bw[t] = (g >= 2) ? (unsigned)vB : (unsigned)vA;
      }
      u32x4 tmp = {bw[0], bw[1], bw[2], bw[3]};
      const bf16x8 pb = __builtin_bit_cast(bf16x8, tmp);
      // out^T += Vt_frag * P^T : A = Vt rows d, k = kv
#pragma unroll
      for (int f = 0; f < 4; ++f) {
        bf16x8 vf = *(const bf16x8*)&Vp[(size_t)(f * 16 + qi) * kS + kv0 + c * 32 + g * 8];
        acc[f] = MFMA16(vf, pb, acc[f]);
      }
    }
  }

  const float rinv = 1.0f / den;
  __bf16* Op = Ob + (size_t)(b * kS + q) * kE + h * kD;
#pragma unroll
  for (int f = 0; f < 4; ++f)
#pragma unroll
    for (int r = 0; r < 4; ++r)
      Op[f * 16 + g * 4 + r] = (__bf16)(acc[f][r] * rinv);
}

// ---------------------------------------------------------------------------
extern "C" void kernel_launch(void* const* d_in, const int* in_sizes, int n_in,
                              void* d_out, int out_size, void* d_ws, size_t ws_size,
                              hipStream_t stream) {
  (void)in_sizes; (void)n_in; (void)out_size; (void)ws_size;
  const float* q  = (const float*)d_in[0];
  const float* k  = (const float*)d_in[1];
  const float* v  = (const float*)d_in[2];
  const int*   mask = (const int*)d_in[3];
  const float* Wq = (const float*)d_in[4];
  const float* bq = (const float*)d_in[5];
  const float* Wk = (const float*)d_in[6];
  const float* bk = (const float*)d_in[7];
  const float* Wv = (const float*)d_in[8];
  const float* bv = (const float*)d_in[9];
  const float* Wo = (const float*)d_in[10];
  const float* bo = (const float*)d_in[11];

  char* ws = (char*)d_ws;
  const size_t MB = 1024 * 1024;
  __bf16* qb  = (__bf16*)(ws + 0 * MB);    // 8MB  [4096,1024]
  __bf16* kb  = (__bf16*)(ws + 8 * MB);    // 8MB
  __bf16* vb  = (__bf16*)(ws + 16 * MB);   // 8MB
  __bf16* wqb = (__bf16*)(ws + 24 * MB);   // 2MB
  __bf16* wkb = (__bf16*)(ws + 26 * MB);   // 2MB
  __bf16* wvb = (__bf16*)(ws + 28 * MB);   // 2MB
  __bf16* wob = (__bf16*)(ws + 30 * MB);   // 2MB
  __bf16* Qh  = (__bf16*)(ws + 32 * MB);   // 8MB [B,H,S,D]
  __bf16* Kh  = (__bf16*)(ws + 40 * MB);   // 8MB [B,H,S,D]
  __bf16* Vt  = (__bf16*)(ws + 48 * MB);   // 8MB [B,H,D,S]
  unsigned long long* mwords = (unsigned long long*)(ws + 56 * MB);  // 1MB
  __bf16* Ob = qb;  // qb is dead after the proj GEMM; reuse for attention out

  cvt_kernel<<<dim3(256, 7), 256, 0, stream>>>(q, k, v, Wq, Wk, Wv, Wo,
                                               qb, kb, vb, wqb, wkb, wvb, wob);
  pack_mask_kernel<<<256, 256, 0, stream>>>(mask, mwords);
  gemm_bt<<<dim3(8, 32, 3), 256, 0, stream>>>(qb, kb, vb, wqb, wkb, wvb,
                                              bq, bk, bv, Qh, Kh, Vt, nullptr, 0);
  attn_kernel<<<dim3(32, 32), 256, 0, stream>>>(Qh, Kh, Vt, mwords, Ob);
  gemm_bt<<<dim3(8, 32, 1), 256, 0, stream>>>(Ob, Ob, Ob, wob, wob, wob,
                                              bo, bo, bo, nullptr, nullptr, nullptr,
                                              (float*)d_out, 3);
}